// Round 2
// baseline (423.630 us; speedup 1.0000x reference)
//
#include <hip/hip_runtime.h>

// ---------- common ----------
typedef __bf16 bfv8 __attribute__((ext_vector_type(8)));
typedef float f32x4 __attribute__((ext_vector_type(4)));

#define DMODEL 2048
#define NHEADS 16
#define HEADD 128
#define SEQ 2048
#define BATCH 2
#define MROWS (BATCH * SEQ)   // 4096

__device__ __forceinline__ unsigned short f2bf(float f) {
    unsigned int x = __float_as_uint(f);
    x += 0x7fffu + ((x >> 16) & 1u);   // round-to-nearest-even
    return (unsigned short)(x >> 16);
}
__device__ __forceinline__ float bf2f(unsigned short u) {
    return __uint_as_float((unsigned int)u << 16);
}
__device__ __forceinline__ unsigned int pk2(float a, float b) {
    return (unsigned int)f2bf(a) | ((unsigned int)f2bf(b) << 16);
}

// ---------- fused fp32 -> bf16 convert for x + 4 weights (dst contiguous in ws) ----------
__global__ __launch_bounds__(256) void cvt_all(const float* __restrict__ x,
                                               const float* __restrict__ wq,
                                               const float* __restrict__ wk,
                                               const float* __restrict__ wv,
                                               const float* __restrict__ wo,
                                               unsigned short* __restrict__ dst) {
    int bid = blockIdx.x;
    const float* s;
    int off;
    if (bid < 8192)       { s = x;  off = bid; }
    else if (bid < 12288) { s = wq; off = bid - 8192; }
    else if (bid < 16384) { s = wk; off = bid - 12288; }
    else if (bid < 20480) { s = wv; off = bid - 16384; }
    else                  { s = wo; off = bid - 20480; }
    int i = off * 1024 + threadIdx.x * 4;
    float4 v = *(const float4*)(s + i);
    ushort4 o;
    o.x = f2bf(v.x); o.y = f2bf(v.y); o.z = f2bf(v.z); o.w = f2bf(v.w);
    *(ushort4*)(dst + (size_t)bid * 1024 + threadIdx.x * 4) = o;
}

// ============================================================
// global_load_lds staging into XOR-swizzled unpadded LDS.
// CPRL = log2(16B-chunks per row). Stored chunk c holds global
// chunk g = c ^ (row & 7).
// ============================================================
template <int CPRL, int ITERS>
__device__ __forceinline__ void stage_n(const unsigned short* __restrict__ gbase,
                                        unsigned short* lds, size_t strideShorts,
                                        int wave, int lane) {
#pragma unroll
    for (int i = 0; i < ITERS; ++i) {
        int L = wave * (64 * ITERS) + i * 64 + lane;
        int m = L >> CPRL, c = L & ((1 << CPRL) - 1);
        int g = c ^ (m & 7);
        const unsigned short* gp = gbase + (size_t)m * strideShorts + g * 8;
        __builtin_amdgcn_global_load_lds(
            (const __attribute__((address_space(1))) unsigned int*)gp,
            (__attribute__((address_space(3))) unsigned int*)(lds + (size_t)(wave * (64 * ITERS) + i * 64) * 8),
            16, 0, 0);
    }
}

#define GBK 64
#define QNT (DMODEL / 64)   // 32 K-tiles for the 256^2 kernel

// ============================================================
// fused QKV GEMM, 256x256 tile / 8-wave / counted-vmcnt schedule.
// A[4096][2048] x Wcat[6144][2048]^T. N-region 0->Q, 1->K, 2->V^T.
// Schedule per K-tile t (slot s=t&1), race-free by construction:
//   PhA: stage hB0(t+1)->slot s^1 (no reader conflict: tile t reads slot s);
//        ds_read a[0..3],b[0..1]; 16 MFMA (prio 1)
//   PhB: stage hB1(t+1)->s^1; ds_read a[4..7],b[2..3]; 16 MFMA
//   lgkmcnt(0); s_barrier        <- all waves done reading slot s
//   PhC: stage hA0(t+2)->slot s (now safe); 16 MFMA
//   PhD: stage hA1(t+2)->slot s; 16 MFMA
//   vmcnt(4); s_barrier          <- tile t+1 landed; hA(t+2) stays in flight
// ============================================================
__global__ __launch_bounds__(512, 2) void gemm_qkv(const unsigned short* __restrict__ A,
                                                   const unsigned short* __restrict__ Bw,
                                                   unsigned short* __restrict__ Qb,
                                                   unsigned short* __restrict__ Kb,
                                                   unsigned short* __restrict__ VT) {
    __shared__ __align__(16) unsigned short LA[2][256 * 64];   // 64 KB
    __shared__ __align__(16) unsigned short LB[2][256 * 64];   // 64 KB
    const int K = DMODEL;
    int tid  = threadIdx.x;
    int wave = tid >> 6, lane = tid & 63;
    int wr = wave >> 2, wc = wave & 3;        // 2 x 4 wave grid
    int wm = wr * 128, wn = wc * 64;          // per-wave C = 128 x 64
    int lr = lane & 15, lg = lane >> 4, lsw = lr & 7;
    int bm = blockIdx.y * 256, bn = blockIdx.x * 256;

    const unsigned short* Ab = A  + (size_t)bm * K;
    const unsigned short* Bb = Bw + (size_t)bn * K;

    f32x4 acc[8][4];
    f32x4 z = {0.f, 0.f, 0.f, 0.f};
#pragma unroll
    for (int i = 0; i < 8; ++i)
#pragma unroll
        for (int j = 0; j < 4; ++j) acc[i][j] = z;

    // ---- prologue: A(0) both halves, B(0) both halves, A(1) both halves (12 loads/thread)
    stage_n<3, 2>(Ab,                        LA[0],            K, wave, lane);
    stage_n<3, 2>(Ab + (size_t)128 * K,      LA[0] + 128 * 64, K, wave, lane);
    stage_n<3, 2>(Bb,                        LB[0],            K, wave, lane);
    stage_n<3, 2>(Bb + (size_t)128 * K,      LB[0] + 128 * 64, K, wave, lane);
    stage_n<3, 2>(Ab + 64,                   LA[1],            K, wave, lane);
    stage_n<3, 2>(Ab + (size_t)128 * K + 64, LA[1] + 128 * 64, K, wave, lane);
    asm volatile("s_waitcnt vmcnt(4)" ::: "memory");   // tile 0 landed; hA(1) in flight
    __builtin_amdgcn_s_barrier();
    __builtin_amdgcn_sched_barrier(0);

#pragma unroll 2
    for (int t = 0; t < QNT; ++t) {
        const unsigned short* As = LA[t & 1];
        const unsigned short* Bs = LB[t & 1];
        unsigned short* AsN = LA[t & 1];           // A(t+2) -> same slot
        unsigned short* BsN = LB[(t & 1) ^ 1];     // B(t+1) -> other slot
        int tA = t + 2; if (tA >= QNT) tA = t;     // tail dummies keep vmcnt uniform
        int tB = t + 1; if (tB >= QNT) tB = t - 1; // (same parity -> same slot, no reader)

        bfv8 a03[4][2], a47[4][2], b01[2][2], b23[2][2];

        // ---- phase A: stage hB0(t+1); read a[0..3], b[0..1]; MFMA (i0-3 x j0-1)
        stage_n<3, 2>(Bb + (size_t)tB * 64, BsN, K, wave, lane);
#pragma unroll
        for (int i = 0; i < 4; ++i)
#pragma unroll
            for (int ks = 0; ks < 2; ++ks)
                a03[i][ks] = *(const bfv8*)&As[(wm + i * 16 + lr) * 64 + ((ks * 4 + lg) ^ lsw) * 8];
#pragma unroll
        for (int j = 0; j < 2; ++j)
#pragma unroll
            for (int ks = 0; ks < 2; ++ks)
                b01[j][ks] = *(const bfv8*)&Bs[(wn + j * 16 + lr) * 64 + ((ks * 4 + lg) ^ lsw) * 8];
        __builtin_amdgcn_sched_barrier(0);
        __builtin_amdgcn_s_setprio(1);
#pragma unroll
        for (int i = 0; i < 4; ++i)
#pragma unroll
            for (int j = 0; j < 2; ++j)
#pragma unroll
                for (int ks = 0; ks < 2; ++ks)
                    acc[i][j] = __builtin_amdgcn_mfma_f32_16x16x32_bf16(a03[i][ks], b01[j][ks], acc[i][j], 0, 0, 0);
        __builtin_amdgcn_s_setprio(0);
        __builtin_amdgcn_sched_barrier(0);

        // ---- phase B: stage hB1(t+1); read a[4..7], b[2..3]; MFMA (i0-3 x j2-3)
        stage_n<3, 2>(Bb + (size_t)128 * K + tB * 64, BsN + 128 * 64, K, wave, lane);
#pragma unroll
        for (int i = 0; i < 4; ++i)
#pragma unroll
            for (int ks = 0; ks < 2; ++ks)
                a47[i][ks] = *(const bfv8*)&As[(wm + 64 + i * 16 + lr) * 64 + ((ks * 4 + lg) ^ lsw) * 8];
#pragma unroll
        for (int j = 0; j < 2; ++j)
#pragma unroll
            for (int ks = 0; ks < 2; ++ks)
                b23[j][ks] = *(const bfv8*)&Bs[(wn + 32 + j * 16 + lr) * 64 + ((ks * 4 + lg) ^ lsw) * 8];
        __builtin_amdgcn_sched_barrier(0);
        __builtin_amdgcn_s_setprio(1);
#pragma unroll
        for (int i = 0; i < 4; ++i)
#pragma unroll
            for (int j = 0; j < 2; ++j)
#pragma unroll
                for (int ks = 0; ks < 2; ++ks)
                    acc[i][2 + j] = __builtin_amdgcn_mfma_f32_16x16x32_bf16(a03[i][ks], b23[j][ks], acc[i][2 + j], 0, 0, 0);
        __builtin_amdgcn_s_setprio(0);
        __builtin_amdgcn_sched_barrier(0);

        asm volatile("s_waitcnt lgkmcnt(0)" ::: "memory");  // my reads of slot s drained
        __builtin_amdgcn_s_barrier();                        // ... all waves' reads drained
        __builtin_amdgcn_sched_barrier(0);

        // ---- phase C: stage hA0(t+2) into freed slot; MFMA (i4-7 x j0-1)
        stage_n<3, 2>(Ab + (size_t)tA * 64, AsN, K, wave, lane);
        __builtin_amdgcn_sched_barrier(0);
        __builtin_amdgcn_s_setprio(1);
#pragma unroll
        for (int i = 0; i < 4; ++i)
#pragma unroll
            for (int j = 0; j < 2; ++j)
#pragma unroll
                for (int ks = 0; ks < 2; ++ks)
                    acc[4 + i][j] = __builtin_amdgcn_mfma_f32_16x16x32_bf16(a47[i][ks], b01[j][ks], acc[4 + i][j], 0, 0, 0);
        __builtin_amdgcn_s_setprio(0);
        __builtin_amdgcn_sched_barrier(0);

        // ---- phase D: stage hA1(t+2); MFMA (i4-7 x j2-3)
        stage_n<3, 2>(Ab + (size_t)128 * K + tA * 64, AsN + 128 * 64, K, wave, lane);
        __builtin_amdgcn_sched_barrier(0);
        __builtin_amdgcn_s_setprio(1);
#pragma unroll
        for (int i = 0; i < 4; ++i)
#pragma unroll
            for (int j = 0; j < 2; ++j)
#pragma unroll
                for (int ks = 0; ks < 2; ++ks)
                    acc[4 + i][2 + j] = __builtin_amdgcn_mfma_f32_16x16x32_bf16(a47[i][ks], b23[j][ks], acc[4 + i][2 + j], 0, 0, 0);
        __builtin_amdgcn_s_setprio(0);
        __builtin_amdgcn_sched_barrier(0);

        asm volatile("s_waitcnt vmcnt(4)" ::: "memory");   // tile t+1 landed; hA(t+2) in flight
        __builtin_amdgcn_s_barrier();
        __builtin_amdgcn_sched_barrier(0);
    }
    asm volatile("s_waitcnt vmcnt(0)" ::: "memory");  // drain tail dummies before LDS dealloc

    // ---- epilogue
    int orow0 = bm + wm + lg * 4;
    int region = bn >> 11;          // block-uniform: 0=Q 1=K 2=V
    int nloc   = bn & 2047;
    if (region < 2) {
        unsigned short* C = region ? Kb : Qb;
#pragma unroll
        for (int i = 0; i < 8; ++i)
#pragma unroll
            for (int j = 0; j < 4; ++j)
#pragma unroll
                for (int r = 0; r < 4; ++r)
                    C[(size_t)(orow0 + i * 16 + r) * DMODEL + nloc + wn + j * 16 + lr] = f2bf(acc[i][j][r]);
    } else {
#pragma unroll
        for (int i = 0; i < 8; ++i) {
            int row = orow0 + i * 16;
            int bb = row >> 11, ss = row & (SEQ - 1);
#pragma unroll
            for (int j = 0; j < 4; ++j) {
                int col = nloc + wn + j * 16 + lr;
                int hh = col >> 7, dd = col & (HEADD - 1);
                ushort4 o4;
                o4.x = f2bf(acc[i][j][0]);
                o4.y = f2bf(acc[i][j][1]);
                o4.z = f2bf(acc[i][j][2]);
                o4.w = f2bf(acc[i][j][3]);
                *(ushort4*)(VT + ((size_t)((bb * NHEADS + hh) * HEADD + dd)) * SEQ + ss) = o4;
            }
        }
    }
}

// ---------- plain GEMM (fp32 out): C[M][N] = A[M][K] * Bw[N][K]^T ----------
__global__ __launch_bounds__(256) void gemm_bt(const unsigned short* __restrict__ A,
                                               const unsigned short* __restrict__ Bw,
                                               float* __restrict__ C,
                                               int M, int N, int K) {
    __shared__ __align__(16) unsigned short As[128 * 64];
    __shared__ __align__(16) unsigned short Bs[128 * 64];
    int tid  = threadIdx.x;
    int bm   = blockIdx.y * 128, bn = blockIdx.x * 128;
    int wave = tid >> 6, lane = tid & 63;
    int wm   = (wave >> 1) * 64, wn = (wave & 1) * 64;
    int lr   = lane & 15, lg = lane >> 4;

    f32x4 acc[4][4];
    f32x4 z = {0.f, 0.f, 0.f, 0.f};
#pragma unroll
    for (int i = 0; i < 4; ++i)
#pragma unroll
        for (int j = 0; j < 4; ++j) acc[i][j] = z;

    const unsigned short* Ab = A  + (size_t)bm * K;
    const unsigned short* Bb = Bw + (size_t)bn * K;

    for (int k0 = 0; k0 < K; k0 += GBK) {
        __syncthreads();
        stage_n<3, 4>(Ab + k0, As, K, wave, lane);
        stage_n<3, 4>(Bb + k0, Bs, K, wave, lane);
        __syncthreads();
#pragma unroll
        for (int kk = 0; kk < GBK; kk += 32) {
            int ck = (kk >> 3) + lg;
            bfv8 af[4], bf[4];
#pragma unroll
            for (int i = 0; i < 4; ++i)
                af[i] = *(const bfv8*)&As[(wm + i * 16 + lr) * 64 + (ck ^ (lr & 7)) * 8];
#pragma unroll
            for (int j = 0; j < 4; ++j)
                bf[j] = *(const bfv8*)&Bs[(wn + j * 16 + lr) * 64 + (ck ^ (lr & 7)) * 8];
#pragma unroll
            for (int i = 0; i < 4; ++i)
#pragma unroll
                for (int j = 0; j < 4; ++j)
                    acc[i][j] = __builtin_amdgcn_mfma_f32_16x16x32_bf16(af[i], bf[j], acc[i][j], 0, 0, 0);
        }
    }
    int orow0 = bm + wm + lg * 4;
    int ocol0 = bn + wn + lr;
#pragma unroll
    for (int i = 0; i < 4; ++i)
#pragma unroll
        for (int j = 0; j < 4; ++j)
#pragma unroll
            for (int r = 0; r < 4; ++r)
                C[(size_t)(orow0 + i * 16 + r) * N + ocol0 + j * 16] = acc[i][j][r];
}

// ---------- RoPE + per-head LayerNorm, in-place on bf16; Q pre-scaled ----------
__global__ __launch_bounds__(256) void rope_ln_ip(unsigned short* __restrict__ qt,
                                                  unsigned short* __restrict__ kt,
                                                  const float* __restrict__ qw,
                                                  const float* __restrict__ kw) {
    int which = blockIdx.y;
    unsigned short* t = which ? kt : qt;
    const float* w = which ? kw : qw;
    float scale = which ? 1.0f : 0.08838834764831845f;   // fold 1/sqrt(128) into Q
    int gr   = blockIdx.x * 4 + (threadIdx.x >> 6);
    int lane = threadIdx.x & 63;
    int m = gr >> 4;
    int h = gr & 15;
    int s = m & (SEQ - 1);
    unsigned short* p = t + (size_t)m * DMODEL + h * HEADD + lane * 2;
    ushort2 xv = *(const ushort2*)p;
    float x0 = bf2f(xv.x), x1 = bf2f(xv.y);
    float inv = powf(10000.0f, -(float)lane * (1.0f / 64.0f));
    float ang = (float)s * inv;
    float sn, c;
    sincosf(ang, &sn, &c);
    float y0 = x0 * c - x1 * sn;
    float y1 = x0 * sn + x1 * c;
    float sum = y0 + y1;
    float sq  = y0 * y0 + y1 * y1;
#pragma unroll
    for (int o = 32; o >= 1; o >>= 1) {
        sum += __shfl_xor(sum, o);
        sq  += __shfl_xor(sq, o);
    }
    float mu  = sum * (1.0f / 128.0f);
    float var = sq * (1.0f / 128.0f) - mu * mu;
    float rs  = rsqrtf(var + 1e-5f) * scale;
    float2 wv = *(const float2*)(w + lane * 2);
    ushort2 ov;
    ov.x = f2bf((y0 - mu) * rs * wv.x);
    ov.y = f2bf((y1 - mu) * rs * wv.y);
    *(ushort2*)p = ov;
}

// ---------- bf16 MFMA flash attention (sliding window), S^T compute ----------
#define AQT 64
#define AKT 64

__global__ __launch_bounds__(256) void attn_mfma(const unsigned short* __restrict__ qb,
                                                 const unsigned short* __restrict__ kb,
                                                 const unsigned short* __restrict__ vt,
                                                 unsigned short* __restrict__ ob,
                                                 const int* __restrict__ wptr) {
    __shared__ __align__(16) unsigned short Ks[64 * 128];    // K tile, swizzled, 16 KB
    __shared__ __align__(16) unsigned short Vs[128 * 64];    // V^T tile, swizzled, 16 KB
    __shared__ __align__(16) unsigned short Ps[4 * 16 * 64]; // per-wave P, swizzled, 8 KB
    int tid  = threadIdx.x;
    int wq   = tid >> 6, lane = tid & 63;
    int lm   = lane & 15, lg = lane >> 4;
    int lm7  = lm & 7;
    // XCD-grouped, heavy-first scheduling
    int gid  = blockIdx.x;
    int xcd  = gid & 7, slot = gid >> 3;
    int bh   = xcd * 4 + (slot >> 5);
    int b    = bh >> 4, h = bh & 15;
    int q0   = (31 - (slot & 31)) * AQT;
    int W    = *wptr;
    unsigned short* PsW = &Ps[wq * 1024];

    // Q B-fragments (16 queries/wave); 1/sqrt(d) pre-folded into Q
    bfv8 qa[4];
    {
        const unsigned short* qp = qb + (size_t)(b * SEQ + q0 + wq * 16 + lm) * DMODEL + h * HEADD + lg * 8;
#pragma unroll
        for (int kk = 0; kk < 4; ++kk) qa[kk] = *(const bfv8*)(qp + kk * 32);
    }

    f32x4 o[8];
    f32x4 z = {0.f, 0.f, 0.f, 0.f};
#pragma unroll
    for (int n = 0; n < 8; ++n) o[n] = z;
    float mrow = -1e30f, lrow = 0.f;   // per-lane state for query lm (replicated over lg)

    const unsigned short* kbase = kb + (size_t)(b * SEQ) * DMODEL + h * HEADD;
    const unsigned short* vbase = vt + (size_t)((b * NHEADS + h) * HEADD) * SEQ;

    int kt_lo = max(0, q0 - W) & ~(AKT - 1);
    int qi = q0 + wq * 16 + lm;

    for (int kt = kt_lo; kt < q0 + AQT; kt += AKT) {
        __syncthreads();
        stage_n<4, 4>(kbase + (size_t)kt * DMODEL, Ks, DMODEL, wq, lane);  // 64 x 128
        stage_n<3, 4>(vbase + kt, Vs, SEQ, wq, lane);                      // 128 x 64
        __syncthreads();

        // S^T = K Q^T : D[m=key][n=query], 64x16 per wave
        f32x4 s[4];
#pragma unroll
        for (int j = 0; j < 4; ++j) s[j] = z;
#pragma unroll
        for (int kk = 0; kk < 4; ++kk) {
#pragma unroll
            for (int j = 0; j < 4; ++j) {
                int ck = (kk * 4 + lg) ^ lm7;
                bfv8 af = *(const bfv8*)&Ks[(j * 16 + lm) * 128 + ck * 8];
                s[j] = __builtin_amdgcn_mfma_f32_16x16x32_bf16(af, qa[kk], s[j], 0, 0, 0);
            }
        }
        // mask only edge tiles (wave-uniform branch)
        if ((kt + 63 >= q0) || (kt < q0 + 63 - W)) {
#pragma unroll
            for (int j = 0; j < 4; ++j) {
                int kj0 = kt + j * 16 + lg * 4;
#pragma unroll
                for (int r = 0; r < 4; ++r) {
                    bool ok = (kj0 + r <= qi) && (kj0 + r >= qi - W);
                    s[j][r] = ok ? s[j][r] : -1e30f;
                }
            }
        }
        // online softmax: one query per lane, reduce across lg (masks 16, 32)
        float mx = -1e30f;
#pragma unroll
        for (int j = 0; j < 4; ++j)
#pragma unroll
            for (int r = 0; r < 4; ++r) mx = fmaxf(mx, s[j][r]);
        mx = fmaxf(mx, __shfl_xor(mx, 16));
        mx = fmaxf(mx, __shfl_xor(mx, 32));
        float mnew  = fmaxf(mrow, mx);
        float alpha = __expf(mrow - mnew);
        mrow = mnew;
        float ls = 0.f;
#pragma unroll
        for (int j = 0; j < 4; ++j) {
            float p0 = __expf(s[j][0] - mnew);
            float p1 = __expf(s[j][1] - mnew);
            float p2 = __expf(s[j][2] - mnew);
            float p3 = __expf(s[j][3] - mnew);
            ls += (p0 + p1) + (p2 + p3);
            // P^T C-layout rows = 4 consecutive keys -> one packed b64 store
            int c0 = (j * 2 + (lg >> 1)) ^ lm7;
            uint2 wv;
            wv.x = pk2(p0, p1);
            wv.y = pk2(p2, p3);
            *(uint2*)&PsW[lm * 64 + c0 * 8 + (lg & 1) * 4] = wv;
        }
        ls += __shfl_xor(ls, 16);
        ls += __shfl_xor(ls, 32);
        lrow = lrow * alpha + ls;
        // broadcast alpha from softmax layout (query=lm) to O layout (query=lg*4+r)
        float al[4];
#pragma unroll
        for (int r = 0; r < 4; ++r) al[r] = __shfl(alpha, lg * 4 + r);
#pragma unroll
        for (int n = 0; n < 8; ++n)
#pragma unroll
            for (int r = 0; r < 4; ++r) o[n][r] *= al[r];
        // O += P V : A = P (wave-private LDS, same-wave ordering), B = V^T
#pragma unroll
        for (int k2 = 0; k2 < 2; ++k2) {
            int cc = (k2 * 4 + lg) ^ lm7;
            bfv8 pa = *(const bfv8*)&PsW[lm * 64 + cc * 8];
#pragma unroll
            for (int n = 0; n < 8; ++n) {
                bfv8 vf = *(const bfv8*)&Vs[(n * 16 + lm) * 64 + cc * 8];
                o[n] = __builtin_amdgcn_mfma_f32_16x16x32_bf16(pa, vf, o[n], 0, 0, 0);
            }
        }
    }
    // epilogue
    float linv[4];
#pragma unroll
    for (int r = 0; r < 4; ++r) linv[r] = 1.0f / __shfl(lrow, lg * 4 + r);
    int qrow = q0 + wq * 16 + lg * 4;
    unsigned short* op = ob + (size_t)(b * SEQ + qrow) * DMODEL + h * HEADD + lm;
#pragma unroll
    for (int n = 0; n < 8; ++n)
#pragma unroll
        for (int r = 0; r < 4; ++r)
            op[(size_t)r * DMODEL + n * 16] = f2bf(o[n][r] * linv[r]);
}

// ---------- launch ----------
extern "C" void kernel_launch(void* const* d_in, const int* in_sizes, int n_in,
                              void* d_out, int out_size, void* d_ws, size_t ws_size,
                              hipStream_t stream) {
    const float* x   = (const float*)d_in[0];
    const float* wq  = (const float*)d_in[1];
    const float* wk  = (const float*)d_in[2];
    const float* wv  = (const float*)d_in[3];
    const float* wo  = (const float*)d_in[4];
    const float* qnw = (const float*)d_in[5];
    const float* knw = (const float*)d_in[6];
    const int*   wsz = (const int*)d_in[7];
    float* out = (float*)d_out;

    // workspace layout (~101 MB); cvt_all dst = [xb | w1 | w2 | w3 | w4] contiguous
    char* ws = (char*)d_ws;
    unsigned short* xb  = (unsigned short*)(ws);                 // 16.78 MB (x bf16; reused for attn out)
    unsigned short* w1  = (unsigned short*)(ws + 16777216);      // wq \  contiguous ->
    unsigned short* w4  = (unsigned short*)(ws + 41943040);      // wo
    unsigned short* qbf = (unsigned short*)(ws + 50331648);      // 16.78 MB bf16 Q
    unsigned short* kbf = (unsigned short*)(ws + 67108864);      // 16.78 MB bf16 K
    unsigned short* vtb = (unsigned short*)(ws + 83886080);      // 16.78 MB bf16 V^T

    cvt_all<<<24576, 256, 0, stream>>>(x, wq, wk, wv, wo, xb);

    gemm_qkv<<<dim3(3 * DMODEL / 256, MROWS / 256), 512, 0, stream>>>(xb, w1, qbf, kbf, vtb);

    rope_ln_ip<<<dim3(MROWS * NHEADS / 4, 2), 256, 0, stream>>>(qbf, kbf, qnw, knw);

    attn_mfma<<<(SEQ / AQT) * NHEADS * BATCH, 256, 0, stream>>>(qbf, kbf, vtb, xb, wsz);

    gemm_bt<<<dim3(DMODEL / 128, MROWS / 128), 256, 0, stream>>>(xb, w4, out, MROWS, DMODEL, DMODEL);
}

// Round 3
// 421.850 us; speedup vs baseline: 1.0042x; 1.0042x over previous
//
#include <hip/hip_runtime.h>

// ---------- common ----------
typedef __bf16 bfv8 __attribute__((ext_vector_type(8)));
typedef float f32x4 __attribute__((ext_vector_type(4)));

#define DMODEL 2048
#define NHEADS 16
#define HEADD 128
#define SEQ 2048
#define BATCH 2
#define MROWS (BATCH * SEQ)   // 4096

__device__ __forceinline__ unsigned short f2bf(float f) {
    unsigned int x = __float_as_uint(f);
    x += 0x7fffu + ((x >> 16) & 1u);   // round-to-nearest-even
    return (unsigned short)(x >> 16);
}
__device__ __forceinline__ float bf2f(unsigned short u) {
    return __uint_as_float((unsigned int)u << 16);
}
__device__ __forceinline__ unsigned int pk2(float a, float b) {
    return (unsigned int)f2bf(a) | ((unsigned int)f2bf(b) << 16);
}

// ---------- fused fp32 -> bf16 convert for x + 4 weights (dst contiguous in ws) ----------
__global__ __launch_bounds__(256) void cvt_all(const float* __restrict__ x,
                                               const float* __restrict__ wq,
                                               const float* __restrict__ wk,
                                               const float* __restrict__ wv,
                                               const float* __restrict__ wo,
                                               unsigned short* __restrict__ dst) {
    int bid = blockIdx.x;
    const float* s;
    int off;
    if (bid < 8192)       { s = x;  off = bid; }
    else if (bid < 12288) { s = wq; off = bid - 8192; }
    else if (bid < 16384) { s = wk; off = bid - 12288; }
    else if (bid < 20480) { s = wv; off = bid - 16384; }
    else                  { s = wo; off = bid - 20480; }
    int i = off * 1024 + threadIdx.x * 4;
    float4 v = *(const float4*)(s + i);
    ushort4 o;
    o.x = f2bf(v.x); o.y = f2bf(v.y); o.z = f2bf(v.z); o.w = f2bf(v.w);
    *(ushort4*)(dst + (size_t)bid * 1024 + threadIdx.x * 4) = o;
}

// ============================================================
// global_load_lds staging into XOR-swizzled unpadded LDS.
// CPRL = log2(16B-chunks per row). Stored chunk c holds global
// chunk g = c ^ (row & 7).  (used by gemm_bt / attn)
// ============================================================
template <int CPRL, int ITERS>
__device__ __forceinline__ void stage_n(const unsigned short* __restrict__ gbase,
                                        unsigned short* lds, size_t strideShorts,
                                        int wave, int lane) {
#pragma unroll
    for (int i = 0; i < ITERS; ++i) {
        int L = wave * (64 * ITERS) + i * 64 + lane;
        int m = L >> CPRL, c = L & ((1 << CPRL) - 1);
        int g = c ^ (m & 7);
        const unsigned short* gp = gbase + (size_t)m * strideShorts + g * 8;
        __builtin_amdgcn_global_load_lds(
            (const __attribute__((address_space(1))) unsigned int*)gp,
            (__attribute__((address_space(3))) unsigned int*)(lds + (size_t)(wave * (64 * ITERS) + i * 64) * 8),
            16, 0, 0);
    }
}

// ---------- 16 KB K-half stage unit for the 8-phase QKV GEMM ----------
// 256 rows x 32 cols bf16; 4 chunks/row; stored chunk c holds global
// chunk c ^ ((row>>2)&3)  -> 2-way bank aliasing on ds_read (free).
template <int ITERS>
__device__ __forceinline__ void stage_k(const unsigned short* __restrict__ gbase,
                                        unsigned short* lds, int strideShorts,
                                        int wave, int lane) {
#pragma unroll
    for (int i = 0; i < ITERS; ++i) {
        int L = wave * (64 * ITERS) + i * 64 + lane;
        int m = L >> 2, c = L & 3;
        int g = c ^ ((m >> 2) & 3);
        const unsigned short* gp = gbase + (size_t)m * strideShorts + g * 8;
        __builtin_amdgcn_global_load_lds(
            (const __attribute__((address_space(1))) unsigned int*)gp,
            (__attribute__((address_space(3))) unsigned int*)(lds + (size_t)(wave * (64 * ITERS) + i * 64) * 8),
            16, 0, 0);
    }
}

#define GBK 64
#define QNT (DMODEL / 64)   // 32 K-tiles

// ============================================================
// fused QKV GEMM, 256x256 tile / 8-wave / m201-style 8-phase schedule.
// LDS regions per slot: 0=A_ks0 1=A_ks1 2=B_ks0 3=B_ks1 (16 KB each).
// Per phase: stage 1 unit -> dead region; ds_read this phase's frags;
// barrier; lgkm(0); setprio(1); 16 MFMA; setprio(0); barrier.
// vmcnt(8) at every even-phase end (4 units in flight; consumed unit
// is issued 6 phases earlier -> always landed). Ledger verified:
// every phase's read regions are disjoint from the <=10 outstanding
// DMA targets at that point.
// ============================================================
#define PHASE(SLOT, KS, IH, READB, STDST, STSRC)                                        \
    do {                                                                                \
        stage_k<2>((STSRC), (STDST), K, wave, lane);                                    \
        if (READB) {                                                                    \
            _Pragma("unroll") for (int j = 0; j < 4; ++j)                               \
                bf[j] = *(const bfv8*)&L[SLOT][2 + KS][(wn + j * 16 + lr) * 32 + coff]; \
        }                                                                               \
        _Pragma("unroll") for (int i = 0; i < 4; ++i)                                   \
            af[i] = *(const bfv8*)&L[SLOT][KS][(wm + (IH) * 64 + i * 16 + lr) * 32 + coff]; \
        __builtin_amdgcn_sched_barrier(0);                                              \
        __builtin_amdgcn_s_barrier();                                                   \
        asm volatile("s_waitcnt lgkmcnt(0)" ::: "memory");                              \
        __builtin_amdgcn_sched_barrier(0);                                              \
        __builtin_amdgcn_s_setprio(1);                                                  \
        _Pragma("unroll") for (int i = 0; i < 4; ++i)                                   \
            _Pragma("unroll") for (int j = 0; j < 4; ++j)                               \
                acc[(IH) * 4 + i][j] = __builtin_amdgcn_mfma_f32_16x16x32_bf16(         \
                    af[i], bf[j], acc[(IH) * 4 + i][j], 0, 0, 0);                       \
        __builtin_amdgcn_s_setprio(0);                                                  \
        __builtin_amdgcn_sched_barrier(0);                                              \
    } while (0)

#define BAR_ODD                           \
    __builtin_amdgcn_s_barrier();         \
    __builtin_amdgcn_sched_barrier(0);

#define BAR_EVEN                                        \
    asm volatile("s_waitcnt vmcnt(8)" ::: "memory");    \
    __builtin_amdgcn_s_barrier();                       \
    __builtin_amdgcn_sched_barrier(0);

__global__ __launch_bounds__(512, 2) void gemm_qkv(const unsigned short* __restrict__ A,
                                                   const unsigned short* __restrict__ Bw,
                                                   unsigned short* __restrict__ Qb,
                                                   unsigned short* __restrict__ Kb,
                                                   unsigned short* __restrict__ VT) {
    __shared__ __align__(16) unsigned short L[2][4][256 * 32];   // 128 KB
    const int K = DMODEL;
    int tid  = threadIdx.x;
    int wave = tid >> 6, lane = tid & 63;
    int wr = wave >> 2, wc = wave & 3;        // 2 x 4 wave grid
    int wm = wr * 128, wn = wc * 64;          // per-wave C = 128 x 64
    int lr = lane & 15, lg = lane >> 4;
    int coff = (lg ^ ((lr >> 2) & 3)) * 8;    // swizzled chunk offset (shorts)
    int bm = blockIdx.y * 256, bn = blockIdx.x * 256;

    const unsigned short* Ab = A  + (size_t)bm * K;
    const unsigned short* Bb = Bw + (size_t)bn * K;

    f32x4 acc[8][4];
    f32x4 z = {0.f, 0.f, 0.f, 0.f};
#pragma unroll
    for (int i = 0; i < 8; ++i)
#pragma unroll
        for (int j = 0; j < 4; ++j) acc[i][j] = z;

    // ---- prologue (calendar order): Aks0(0) Bks0(0) Aks1(0) Bks1(0) Aks0(1) Bks0(1)
    stage_k<2>(Ab,      &L[0][0][0], K, wave, lane);
    stage_k<2>(Bb,      &L[0][2][0], K, wave, lane);
    stage_k<2>(Ab + 32, &L[0][1][0], K, wave, lane);
    stage_k<2>(Bb + 32, &L[0][3][0], K, wave, lane);
    stage_k<2>(Ab + 64, &L[1][0][0], K, wave, lane);
    stage_k<2>(Bb + 64, &L[1][2][0], K, wave, lane);
    asm volatile("s_waitcnt vmcnt(8)" ::: "memory");   // ks0(tile0) landed
    __builtin_amdgcn_s_barrier();
    __builtin_amdgcn_sched_barrier(0);

    bfv8 af[4], bf[4];

#pragma unroll 1
    for (int it = 0; it < QNT / 2; ++it) {
        int u  = 2 * it;
        int t1 = u + 1;                                // never exceeds QNT-1
        int t2 = (u + 2 < QNT) ? u + 2 : QNT - 1;      // tail dummies target
        int t3 = (u + 3 < QNT) ? u + 3 : QNT - 1;      // dead regions only

        PHASE(0, 0, 0, true,  &L[1][1][0], Ab + (size_t)t1 * 64 + 32); BAR_ODD;   // ph1
        PHASE(0, 0, 1, false, &L[1][3][0], Bb + (size_t)t1 * 64 + 32); BAR_EVEN;  // ph2
        PHASE(0, 1, 0, true,  &L[0][0][0], Ab + (size_t)t2 * 64);      BAR_ODD;   // ph3
        PHASE(0, 1, 1, false, &L[0][2][0], Bb + (size_t)t2 * 64);      BAR_EVEN;  // ph4
        PHASE(1, 0, 0, true,  &L[0][1][0], Ab + (size_t)t2 * 64 + 32); BAR_ODD;   // ph5
        PHASE(1, 0, 1, false, &L[0][3][0], Bb + (size_t)t2 * 64 + 32); BAR_EVEN;  // ph6
        PHASE(1, 1, 0, true,  &L[1][0][0], Ab + (size_t)t3 * 64);      BAR_ODD;   // ph7
        PHASE(1, 1, 1, false, &L[1][2][0], Bb + (size_t)t3 * 64);      BAR_EVEN;  // ph8
    }
    asm volatile("s_waitcnt vmcnt(0)" ::: "memory");  // drain tail dummies before LDS dealloc

    // ---- epilogue
    int orow0 = bm + wm + lg * 4;
    int region = bn >> 11;          // block-uniform: 0=Q 1=K 2=V
    int nloc   = bn & 2047;
    if (region < 2) {
        unsigned short* C = region ? Kb : Qb;
#pragma unroll
        for (int i = 0; i < 8; ++i)
#pragma unroll
            for (int j = 0; j < 4; ++j)
#pragma unroll
                for (int r = 0; r < 4; ++r)
                    C[(size_t)(orow0 + i * 16 + r) * DMODEL + nloc + wn + j * 16 + lr] = f2bf(acc[i][j][r]);
    } else {
#pragma unroll
        for (int i = 0; i < 8; ++i) {
            int row = orow0 + i * 16;
            int bb = row >> 11, ss = row & (SEQ - 1);
#pragma unroll
            for (int j = 0; j < 4; ++j) {
                int col = nloc + wn + j * 16 + lr;
                int hh = col >> 7, dd = col & (HEADD - 1);
                ushort4 o4;
                o4.x = f2bf(acc[i][j][0]);
                o4.y = f2bf(acc[i][j][1]);
                o4.z = f2bf(acc[i][j][2]);
                o4.w = f2bf(acc[i][j][3]);
                *(ushort4*)(VT + ((size_t)((bb * NHEADS + hh) * HEADD + dd)) * SEQ + ss) = o4;
            }
        }
    }
}

// ---------- plain GEMM (fp32 out): C[M][N] = A[M][K] * Bw[N][K]^T ----------
__global__ __launch_bounds__(256) void gemm_bt(const unsigned short* __restrict__ A,
                                               const unsigned short* __restrict__ Bw,
                                               float* __restrict__ C,
                                               int M, int N, int K) {
    __shared__ __align__(16) unsigned short As[128 * 64];
    __shared__ __align__(16) unsigned short Bs[128 * 64];
    int tid  = threadIdx.x;
    int bm   = blockIdx.y * 128, bn = blockIdx.x * 128;
    int wave = tid >> 6, lane = tid & 63;
    int wm   = (wave >> 1) * 64, wn = (wave & 1) * 64;
    int lr   = lane & 15, lg = lane >> 4;

    f32x4 acc[4][4];
    f32x4 z = {0.f, 0.f, 0.f, 0.f};
#pragma unroll
    for (int i = 0; i < 4; ++i)
#pragma unroll
        for (int j = 0; j < 4; ++j) acc[i][j] = z;

    const unsigned short* Ab = A  + (size_t)bm * K;
    const unsigned short* Bb = Bw + (size_t)bn * K;

    for (int k0 = 0; k0 < K; k0 += GBK) {
        __syncthreads();
        stage_n<3, 4>(Ab + k0, As, K, wave, lane);
        stage_n<3, 4>(Bb + k0, Bs, K, wave, lane);
        __syncthreads();
#pragma unroll
        for (int kk = 0; kk < GBK; kk += 32) {
            int ck = (kk >> 3) + lg;
            bfv8 af[4], bf[4];
#pragma unroll
            for (int i = 0; i < 4; ++i)
                af[i] = *(const bfv8*)&As[(wm + i * 16 + lr) * 64 + (ck ^ (lr & 7)) * 8];
#pragma unroll
            for (int j = 0; j < 4; ++j)
                bf[j] = *(const bfv8*)&Bs[(wn + j * 16 + lr) * 64 + (ck ^ (lr & 7)) * 8];
#pragma unroll
            for (int i = 0; i < 4; ++i)
#pragma unroll
                for (int j = 0; j < 4; ++j)
                    acc[i][j] = __builtin_amdgcn_mfma_f32_16x16x32_bf16(af[i], bf[j], acc[i][j], 0, 0, 0);
        }
    }
    int orow0 = bm + wm + lg * 4;
    int ocol0 = bn + wn + lr;
#pragma unroll
    for (int i = 0; i < 4; ++i)
#pragma unroll
        for (int j = 0; j < 4; ++j)
#pragma unroll
            for (int r = 0; r < 4; ++r)
                C[(size_t)(orow0 + i * 16 + r) * N + ocol0 + j * 16] = acc[i][j][r];
}

// ---------- RoPE + per-head LayerNorm, in-place on bf16; Q pre-scaled ----------
__global__ __launch_bounds__(256) void rope_ln_ip(unsigned short* __restrict__ qt,
                                                  unsigned short* __restrict__ kt,
                                                  const float* __restrict__ qw,
                                                  const float* __restrict__ kw) {
    int which = blockIdx.y;
    unsigned short* t = which ? kt : qt;
    const float* w = which ? kw : qw;
    float scale = which ? 1.0f : 0.08838834764831845f;   // fold 1/sqrt(128) into Q
    int gr   = blockIdx.x * 4 + (threadIdx.x >> 6);
    int lane = threadIdx.x & 63;
    int m = gr >> 4;
    int h = gr & 15;
    int s = m & (SEQ - 1);
    unsigned short* p = t + (size_t)m * DMODEL + h * HEADD + lane * 2;
    ushort2 xv = *(const ushort2*)p;
    float x0 = bf2f(xv.x), x1 = bf2f(xv.y);
    float inv = powf(10000.0f, -(float)lane * (1.0f / 64.0f));
    float ang = (float)s * inv;
    float sn, c;
    sincosf(ang, &sn, &c);
    float y0 = x0 * c - x1 * sn;
    float y1 = x0 * sn + x1 * c;
    float sum = y0 + y1;
    float sq  = y0 * y0 + y1 * y1;
#pragma unroll
    for (int o = 32; o >= 1; o >>= 1) {
        sum += __shfl_xor(sum, o);
        sq  += __shfl_xor(sq, o);
    }
    float mu  = sum * (1.0f / 128.0f);
    float var = sq * (1.0f / 128.0f) - mu * mu;
    float rs  = rsqrtf(var + 1e-5f) * scale;
    float2 wv = *(const float2*)(w + lane * 2);
    ushort2 ov;
    ov.x = f2bf((y0 - mu) * rs * wv.x);
    ov.y = f2bf((y1 - mu) * rs * wv.y);
    *(ushort2*)p = ov;
}

// ---------- bf16 MFMA flash attention (sliding window), S^T compute ----------
#define AQT 64
#define AKT 64

__global__ __launch_bounds__(256) void attn_mfma(const unsigned short* __restrict__ qb,
                                                 const unsigned short* __restrict__ kb,
                                                 const unsigned short* __restrict__ vt,
                                                 unsigned short* __restrict__ ob,
                                                 const int* __restrict__ wptr) {
    __shared__ __align__(16) unsigned short Ks[64 * 128];    // K tile, swizzled, 16 KB
    __shared__ __align__(16) unsigned short Vs[128 * 64];    // V^T tile, swizzled, 16 KB
    __shared__ __align__(16) unsigned short Ps[4 * 16 * 64]; // per-wave P, swizzled, 8 KB
    int tid  = threadIdx.x;
    int wq   = tid >> 6, lane = tid & 63;
    int lm   = lane & 15, lg = lane >> 4;
    int lm7  = lm & 7;
    // XCD-grouped, heavy-first scheduling
    int gid  = blockIdx.x;
    int xcd  = gid & 7, slot = gid >> 3;
    int bh   = xcd * 4 + (slot >> 5);
    int b    = bh >> 4, h = bh & 15;
    int q0   = (31 - (slot & 31)) * AQT;
    int W    = *wptr;
    unsigned short* PsW = &Ps[wq * 1024];

    // Q B-fragments (16 queries/wave); 1/sqrt(d) pre-folded into Q
    bfv8 qa[4];
    {
        const unsigned short* qp = qb + (size_t)(b * SEQ + q0 + wq * 16 + lm) * DMODEL + h * HEADD + lg * 8;
#pragma unroll
        for (int kk = 0; kk < 4; ++kk) qa[kk] = *(const bfv8*)(qp + kk * 32);
    }

    f32x4 o[8];
    f32x4 z = {0.f, 0.f, 0.f, 0.f};
#pragma unroll
    for (int n = 0; n < 8; ++n) o[n] = z;
    float mrow = -1e30f, lrow = 0.f;   // per-lane state for query lm (replicated over lg)

    const unsigned short* kbase = kb + (size_t)(b * SEQ) * DMODEL + h * HEADD;
    const unsigned short* vbase = vt + (size_t)((b * NHEADS + h) * HEADD) * SEQ;

    int kt_lo = max(0, q0 - W) & ~(AKT - 1);
    int qi = q0 + wq * 16 + lm;

    for (int kt = kt_lo; kt < q0 + AQT; kt += AKT) {
        __syncthreads();
        stage_n<4, 4>(kbase + (size_t)kt * DMODEL, Ks, DMODEL, wq, lane);  // 64 x 128
        stage_n<3, 4>(vbase + kt, Vs, SEQ, wq, lane);                      // 128 x 64
        __syncthreads();

        // S^T = K Q^T : D[m=key][n=query], 64x16 per wave
        f32x4 s[4];
#pragma unroll
        for (int j = 0; j < 4; ++j) s[j] = z;
#pragma unroll
        for (int kk = 0; kk < 4; ++kk) {
#pragma unroll
            for (int j = 0; j < 4; ++j) {
                int ck = (kk * 4 + lg) ^ lm7;
                bfv8 af = *(const bfv8*)&Ks[(j * 16 + lm) * 128 + ck * 8];
                s[j] = __builtin_amdgcn_mfma_f32_16x16x32_bf16(af, qa[kk], s[j], 0, 0, 0);
            }
        }
        // mask only edge tiles (wave-uniform branch)
        if ((kt + 63 >= q0) || (kt < q0 + 63 - W)) {
#pragma unroll
            for (int j = 0; j < 4; ++j) {
                int kj0 = kt + j * 16 + lg * 4;
#pragma unroll
                for (int r = 0; r < 4; ++r) {
                    bool ok = (kj0 + r <= qi) && (kj0 + r >= qi - W);
                    s[j][r] = ok ? s[j][r] : -1e30f;
                }
            }
        }
        // online softmax: one query per lane, reduce across lg (masks 16, 32)
        float mx = -1e30f;
#pragma unroll
        for (int j = 0; j < 4; ++j)
#pragma unroll
            for (int r = 0; r < 4; ++r) mx = fmaxf(mx, s[j][r]);
        mx = fmaxf(mx, __shfl_xor(mx, 16));
        mx = fmaxf(mx, __shfl_xor(mx, 32));
        float mnew  = fmaxf(mrow, mx);
        float alpha = __expf(mrow - mnew);
        mrow = mnew;
        float ls = 0.f;
#pragma unroll
        for (int j = 0; j < 4; ++j) {
            float p0 = __expf(s[j][0] - mnew);
            float p1 = __expf(s[j][1] - mnew);
            float p2 = __expf(s[j][2] - mnew);
            float p3 = __expf(s[j][3] - mnew);
            ls += (p0 + p1) + (p2 + p3);
            // P^T C-layout rows = 4 consecutive keys -> one packed b64 store
            int c0 = (j * 2 + (lg >> 1)) ^ lm7;
            uint2 wv;
            wv.x = pk2(p0, p1);
            wv.y = pk2(p2, p3);
            *(uint2*)&PsW[lm * 64 + c0 * 8 + (lg & 1) * 4] = wv;
        }
        ls += __shfl_xor(ls, 16);
        ls += __shfl_xor(ls, 32);
        lrow = lrow * alpha + ls;
        // broadcast alpha from softmax layout (query=lm) to O layout (query=lg*4+r)
        float al[4];
#pragma unroll
        for (int r = 0; r < 4; ++r) al[r] = __shfl(alpha, lg * 4 + r);
#pragma unroll
        for (int n = 0; n < 8; ++n)
#pragma unroll
            for (int r = 0; r < 4; ++r) o[n][r] *= al[r];
        // O += P V : A = P (wave-private LDS, same-wave ordering), B = V^T
#pragma unroll
        for (int k2 = 0; k2 < 2; ++k2) {
            int cc = (k2 * 4 + lg) ^ lm7;
            bfv8 pa = *(const bfv8*)&PsW[lm * 64 + cc * 8];
#pragma unroll
            for (int n = 0; n < 8; ++n) {
                bfv8 vf = *(const bfv8*)&Vs[(n * 16 + lm) * 64 + cc * 8];
                o[n] = __builtin_amdgcn_mfma_f32_16x16x32_bf16(pa, vf, o[n], 0, 0, 0);
            }
        }
    }
    // epilogue
    float linv[4];
#pragma unroll
    for (int r = 0; r < 4; ++r) linv[r] = 1.0f / __shfl(lrow, lg * 4 + r);
    int qrow = q0 + wq * 16 + lg * 4;
    unsigned short* op = ob + (size_t)(b * SEQ + qrow) * DMODEL + h * HEADD + lm;
#pragma unroll
    for (int n = 0; n < 8; ++n)
#pragma unroll
        for (int r = 0; r < 4; ++r)
            op[(size_t)r * DMODEL + n * 16] = f2bf(o[n][r] * linv[r]);
}

// ---------- launch ----------
extern "C" void kernel_launch(void* const* d_in, const int* in_sizes, int n_in,
                              void* d_out, int out_size, void* d_ws, size_t ws_size,
                              hipStream_t stream) {
    const float* x   = (const float*)d_in[0];
    const float* wq  = (const float*)d_in[1];
    const float* wk  = (const float*)d_in[2];
    const float* wv  = (const float*)d_in[3];
    const float* wo  = (const float*)d_in[4];
    const float* qnw = (const float*)d_in[5];
    const float* knw = (const float*)d_in[6];
    const int*   wsz = (const int*)d_in[7];
    float* out = (float*)d_out;

    // workspace layout (~101 MB); cvt_all dst = [xb | w1 | w2 | w3 | w4] contiguous
    char* ws = (char*)d_ws;
    unsigned short* xb  = (unsigned short*)(ws);                 // 16.78 MB (x bf16; reused for attn out)
    unsigned short* w1  = (unsigned short*)(ws + 16777216);      // wq \  contiguous ->
    unsigned short* w4  = (unsigned short*)(ws + 41943040);      // wo
    unsigned short* qbf = (unsigned short*)(ws + 50331648);      // 16.78 MB bf16 Q
    unsigned short* kbf = (unsigned short*)(ws + 67108864);      // 16.78 MB bf16 K
    unsigned short* vtb = (unsigned short*)(ws + 83886080);      // 16.78 MB bf16 V^T

    cvt_all<<<24576, 256, 0, stream>>>(x, wq, wk, wv, wo, xb);

    gemm_qkv<<<dim3(3 * DMODEL / 256, MROWS / 256), 512, 0, stream>>>(xb, w1, qbf, kbf, vtb);

    rope_ln_ip<<<dim3(MROWS * NHEADS / 4, 2), 256, 0, stream>>>(qbf, kbf, qnw, knw);

    attn_mfma<<<(SEQ / AQT) * NHEADS * BATCH, 256, 0, stream>>>(qbf, kbf, vtb, xb, wsz);

    gemm_bt<<<dim3(DMODEL / 128, MROWS / 128), 256, 0, stream>>>(xb, w4, out, MROWS, DMODEL, DMODEL);
}

// Round 5
// 411.699 us; speedup vs baseline: 1.0290x; 1.0247x over previous
//
#include <hip/hip_runtime.h>

// ---------- common ----------
typedef __bf16 bfv8 __attribute__((ext_vector_type(8)));
typedef float f32x4 __attribute__((ext_vector_type(4)));

#define DMODEL 2048
#define NHEADS 16
#define HEADD 128
#define SEQ 2048
#define BATCH 2
#define MROWS (BATCH * SEQ)   // 4096

__device__ __forceinline__ unsigned short f2bf(float f) {
    unsigned int x = __float_as_uint(f);
    x += 0x7fffu + ((x >> 16) & 1u);   // round-to-nearest-even
    return (unsigned short)(x >> 16);
}
__device__ __forceinline__ float bf2f(unsigned short u) {
    return __uint_as_float((unsigned int)u << 16);
}
__device__ __forceinline__ unsigned int pk2(float a, float b) {
    return (unsigned int)f2bf(a) | ((unsigned int)f2bf(b) << 16);
}

// ---------- fused fp32 -> bf16 convert for x + 4 weights (dst contiguous in ws) ----------
__global__ __launch_bounds__(256) void cvt_all(const float* __restrict__ x,
                                               const float* __restrict__ wq,
                                               const float* __restrict__ wk,
                                               const float* __restrict__ wv,
                                               const float* __restrict__ wo,
                                               unsigned short* __restrict__ dst) {
    int bid = blockIdx.x;
    const float* s;
    int off;
    if (bid < 8192)       { s = x;  off = bid; }
    else if (bid < 12288) { s = wq; off = bid - 8192; }
    else if (bid < 16384) { s = wk; off = bid - 12288; }
    else if (bid < 20480) { s = wv; off = bid - 16384; }
    else                  { s = wo; off = bid - 20480; }
    int i = off * 1024 + threadIdx.x * 4;
    float4 v = *(const float4*)(s + i);
    ushort4 o;
    o.x = f2bf(v.x); o.y = f2bf(v.y); o.z = f2bf(v.z); o.w = f2bf(v.w);
    *(ushort4*)(dst + (size_t)bid * 1024 + threadIdx.x * 4) = o;
}

// ============================================================
// global_load_lds staging into XOR-swizzled unpadded LDS.
// CPRL = log2(16B-chunks per row). Stored chunk c holds global
// chunk g = c ^ (row & 7).  128B rows -> proven 0 bank conflicts.
// ============================================================
template <int CPRL, int ITERS>
__device__ __forceinline__ void stage_n(const unsigned short* __restrict__ gbase,
                                        unsigned short* lds, size_t strideShorts,
                                        int wave, int lane) {
#pragma unroll
    for (int i = 0; i < ITERS; ++i) {
        int L = wave * (64 * ITERS) + i * 64 + lane;
        int m = L >> CPRL, c = L & ((1 << CPRL) - 1);
        int g = c ^ (m & 7);
        const unsigned short* gp = gbase + (size_t)m * strideShorts + g * 8;
        __builtin_amdgcn_global_load_lds(
            (const __attribute__((address_space(1))) unsigned int*)gp,
            (__attribute__((address_space(3))) unsigned int*)(lds + (size_t)(wave * (64 * ITERS) + i * 64) * 8),
            16, 0, 0);
    }
}

#define GBK 64
#define QNT (DMODEL / 64)   // 32 K-tiles

// ============================================================
// fused QKV GEMM, 256x192 tile / 8-wave / counted-vmcnt schedule.
// Grid 32x16 = 512 blocks = EXACTLY 2 dispatch rounds on 256 CUs
// (the 256^2 variant's 384-block grid wasted 25% of CU-time in tail).
// A[4096][2048] x Wcat[6144][2048]^T. Per-wave C = 128x48 (acc[8][3]).
// Schedule per K-tile t (slot s=t&1), round-2-proven, race-free:
//   stage B(t+1)->LB[s^1]; ds_read ks0 frags; 24 MFMA (prio 1);
//   ds_read ks1 frags; 24 MFMA; lgkm(0); barrier;
//   stage A(t+2)->LA[s] (slot just freed); vmcnt(4); barrier.
// vmcnt ledger (loads/thread: A=4, B=3): outstanding 4 -> 7 -> 11,
// wait(4) drains A(t+1)+B(t+1), leaves A(t+2) in flight. Tail iters
// stage value-identical dummies into dead regions to keep counts uniform.
// ============================================================
__global__ __launch_bounds__(512, 2) void gemm_qkv(const unsigned short* __restrict__ A,
                                                   const unsigned short* __restrict__ Bw,
                                                   unsigned short* __restrict__ Qb,
                                                   unsigned short* __restrict__ Kb,
                                                   unsigned short* __restrict__ VT) {
    __shared__ __align__(16) unsigned short LA[2][256 * 64];   // 64 KB
    __shared__ __align__(16) unsigned short LB[2][192 * 64];   // 48 KB
    const int K = DMODEL;
    int tid  = threadIdx.x;
    int wave = tid >> 6, lane = tid & 63;
    int wr = wave >> 2, wc = wave & 3;        // 2 x 4 wave grid
    int wm = wr * 128, wn = wc * 48;          // per-wave C = 128 x 48
    int lr = lane & 15, lg = lane >> 4, lsw = lr & 7;
    int bm = blockIdx.y * 256, bn = blockIdx.x * 192;

    const unsigned short* Ab = A  + (size_t)bm * K;
    const unsigned short* Bb = Bw + (size_t)bn * K;

    f32x4 acc[8][3];
    f32x4 z = {0.f, 0.f, 0.f, 0.f};
#pragma unroll
    for (int i = 0; i < 8; ++i)
#pragma unroll
        for (int j = 0; j < 3; ++j) acc[i][j] = z;

    // ---- prologue: A(0), B(0), A(1)   (11 loads/thread)
    stage_n<3, 4>(Ab,      LA[0], K, wave, lane);
    stage_n<3, 3>(Bb,      LB[0], K, wave, lane);
    stage_n<3, 4>(Ab + 64, LA[1], K, wave, lane);
    asm volatile("s_waitcnt vmcnt(4)" ::: "memory");   // A(0), B(0) landed; A(1) in flight
    __builtin_amdgcn_s_barrier();
    __builtin_amdgcn_sched_barrier(0);

    bfv8 a[8], b[3];

#pragma unroll 2
    for (int t = 0; t < QNT; ++t) {
        const unsigned short* As = LA[t & 1];
        const unsigned short* Bs = LB[t & 1];
        unsigned short* AsN = LA[t & 1];           // A(t+2) -> same slot (freed at mid-barrier)
        unsigned short* BsN = LB[(t & 1) ^ 1];     // B(t+1) -> other slot
        int tB = (t + 1 < QNT) ? t + 1 : QNT - 1;  // tail dummy: dead slot, real data
        int tA = (t + 2 < QNT) ? t + 2 : QNT - 1;

        // ---- stage B(t+1); ks0 reads; 24 MFMA
        stage_n<3, 3>(Bb + (size_t)tB * 64, BsN, K, wave, lane);
#pragma unroll
        for (int i = 0; i < 8; ++i)
            a[i] = *(const bfv8*)&As[(wm + i * 16 + lr) * 64 + (lg ^ lsw) * 8];
#pragma unroll
        for (int j = 0; j < 3; ++j)
            b[j] = *(const bfv8*)&Bs[(wn + j * 16 + lr) * 64 + (lg ^ lsw) * 8];
        __builtin_amdgcn_sched_barrier(0);
        __builtin_amdgcn_s_setprio(1);
#pragma unroll
        for (int i = 0; i < 8; ++i)
#pragma unroll
            for (int j = 0; j < 3; ++j)
                acc[i][j] = __builtin_amdgcn_mfma_f32_16x16x32_bf16(a[i], b[j], acc[i][j], 0, 0, 0);
        __builtin_amdgcn_s_setprio(0);
        __builtin_amdgcn_sched_barrier(0);

        // ---- ks1 reads; 24 MFMA
#pragma unroll
        for (int i = 0; i < 8; ++i)
            a[i] = *(const bfv8*)&As[(wm + i * 16 + lr) * 64 + ((4 + lg) ^ lsw) * 8];
#pragma unroll
        for (int j = 0; j < 3; ++j)
            b[j] = *(const bfv8*)&Bs[(wn + j * 16 + lr) * 64 + ((4 + lg) ^ lsw) * 8];
        __builtin_amdgcn_sched_barrier(0);
        __builtin_amdgcn_s_setprio(1);
#pragma unroll
        for (int i = 0; i < 8; ++i)
#pragma unroll
            for (int j = 0; j < 3; ++j)
                acc[i][j] = __builtin_amdgcn_mfma_f32_16x16x32_bf16(a[i], b[j], acc[i][j], 0, 0, 0);
        __builtin_amdgcn_s_setprio(0);
        __builtin_amdgcn_sched_barrier(0);

        asm volatile("s_waitcnt lgkmcnt(0)" ::: "memory");  // my reads of slot s drained
        __builtin_amdgcn_s_barrier();                        // all waves' reads drained
        __builtin_amdgcn_sched_barrier(0);

        // ---- stage A(t+2) into the slot just freed; counted drain
        stage_n<3, 4>(Ab + (size_t)tA * 64, AsN, K, wave, lane);
        asm volatile("s_waitcnt vmcnt(4)" ::: "memory");    // A(t+1)+B(t+1) landed; A(t+2) flying
        __builtin_amdgcn_s_barrier();
        __builtin_amdgcn_sched_barrier(0);
    }
    asm volatile("s_waitcnt vmcnt(0)" ::: "memory");  // drain tail dummies

    // ---- epilogue: per-j region dispatch (192-tiles may straddle Q/K/V)
    int orow0 = bm + wm + lg * 4;
#pragma unroll
    for (int i = 0; i < 8; ++i) {
        int row = orow0 + i * 16;
        int bb = row >> 11, ss = row & (SEQ - 1);
#pragma unroll
        for (int j = 0; j < 3; ++j) {
            int col0 = bn + wn + j * 16;       // multiple of 16; region uniform over lanes
            int region = col0 >> 11;           // 0=Q 1=K 2=V
            if (region < 2) {
                unsigned short* C = region ? Kb : Qb;
#pragma unroll
                for (int r = 0; r < 4; ++r)
                    C[(size_t)(row + r) * DMODEL + (col0 & 2047) + lr] = f2bf(acc[i][j][r]);
            } else {
                int colf = col0 + lr;
                int hh = (colf >> 7) & 15, dd = colf & (HEADD - 1);
                ushort4 o4;
                o4.x = f2bf(acc[i][j][0]);
                o4.y = f2bf(acc[i][j][1]);
                o4.z = f2bf(acc[i][j][2]);
                o4.w = f2bf(acc[i][j][3]);
                *(ushort4*)(VT + ((size_t)((bb * NHEADS + hh) * HEADD + dd)) * SEQ + ss) = o4;
            }
        }
    }
}

// ---------- plain GEMM (fp32 out): C[M][N] = A[M][K] * Bw[N][K]^T ----------
__global__ __launch_bounds__(256) void gemm_bt(const unsigned short* __restrict__ A,
                                               const unsigned short* __restrict__ Bw,
                                               float* __restrict__ C,
                                               int M, int N, int K) {
    __shared__ __align__(16) unsigned short As[128 * 64];
    __shared__ __align__(16) unsigned short Bs[128 * 64];
    int tid  = threadIdx.x;
    int bm   = blockIdx.y * 128, bn = blockIdx.x * 128;
    int wave = tid >> 6, lane = tid & 63;
    int wm   = (wave >> 1) * 64, wn = (wave & 1) * 64;
    int lr   = lane & 15, lg = lane >> 4;

    f32x4 acc[4][4];
    f32x4 z = {0.f, 0.f, 0.f, 0.f};
#pragma unroll
    for (int i = 0; i < 4; ++i)
#pragma unroll
        for (int j = 0; j < 4; ++j) acc[i][j] = z;

    const unsigned short* Ab = A  + (size_t)bm * K;
    const unsigned short* Bb = Bw + (size_t)bn * K;

    for (int k0 = 0; k0 < K; k0 += GBK) {
        __syncthreads();
        stage_n<3, 4>(Ab + k0, As, K, wave, lane);
        stage_n<3, 4>(Bb + k0, Bs, K, wave, lane);
        __syncthreads();
#pragma unroll
        for (int kk = 0; kk < GBK; kk += 32) {
            int ck = (kk >> 3) + lg;
            bfv8 af[4], bf[4];
#pragma unroll
            for (int i = 0; i < 4; ++i)
                af[i] = *(const bfv8*)&As[(wm + i * 16 + lr) * 64 + (ck ^ (lr & 7)) * 8];
#pragma unroll
            for (int j = 0; j < 4; ++j)
                bf[j] = *(const bfv8*)&Bs[(wn + j * 16 + lr) * 64 + (ck ^ (lr & 7)) * 8];
#pragma unroll
            for (int i = 0; i < 4; ++i)
#pragma unroll
                for (int j = 0; j < 4; ++j)
                    acc[i][j] = __builtin_amdgcn_mfma_f32_16x16x32_bf16(af[i], bf[j], acc[i][j], 0, 0, 0);
        }
    }
    int orow0 = bm + wm + lg * 4;
    int ocol0 = bn + wn + lr;
#pragma unroll
    for (int i = 0; i < 4; ++i)
#pragma unroll
        for (int j = 0; j < 4; ++j)
#pragma unroll
            for (int r = 0; r < 4; ++r)
                C[(size_t)(orow0 + i * 16 + r) * N + ocol0 + j * 16] = acc[i][j][r];
}

// ---------- RoPE + per-head LayerNorm, in-place on bf16; Q pre-scaled ----------
__global__ __launch_bounds__(256) void rope_ln_ip(unsigned short* __restrict__ qt,
                                                  unsigned short* __restrict__ kt,
                                                  const float* __restrict__ qw,
                                                  const float* __restrict__ kw) {
    int which = blockIdx.y;
    unsigned short* t = which ? kt : qt;
    const float* w = which ? kw : qw;
    float scale = which ? 1.0f : 0.08838834764831845f;   // fold 1/sqrt(128) into Q
    int gr   = blockIdx.x * 4 + (threadIdx.x >> 6);
    int lane = threadIdx.x & 63;
    int m = gr >> 4;
    int h = gr & 15;
    int s = m & (SEQ - 1);
    unsigned short* p = t + (size_t)m * DMODEL + h * HEADD + lane * 2;
    ushort2 xv = *(const ushort2*)p;
    float x0 = bf2f(xv.x), x1 = bf2f(xv.y);
    float inv = powf(10000.0f, -(float)lane * (1.0f / 64.0f));
    float ang = (float)s * inv;
    float sn, c;
    sincosf(ang, &sn, &c);
    float y0 = x0 * c - x1 * sn;
    float y1 = x0 * sn + x1 * c;
    float sum = y0 + y1;
    float sq  = y0 * y0 + y1 * y1;
#pragma unroll
    for (int o = 32; o >= 1; o >>= 1) {
        sum += __shfl_xor(sum, o);
        sq  += __shfl_xor(sq, o);
    }
    float mu  = sum * (1.0f / 128.0f);
    float var = sq * (1.0f / 128.0f) - mu * mu;
    float rs  = rsqrtf(var + 1e-5f) * scale;
    float2 wv = *(const float2*)(w + lane * 2);
    ushort2 ov;
    ov.x = f2bf((y0 - mu) * rs * wv.x);
    ov.y = f2bf((y1 - mu) * rs * wv.y);
    *(ushort2*)p = ov;
}

// ---------- bf16 MFMA flash attention (sliding window), S^T compute ----------
#define AQT 64
#define AKT 64

__global__ __launch_bounds__(256) void attn_mfma(const unsigned short* __restrict__ qb,
                                                 const unsigned short* __restrict__ kb,
                                                 const unsigned short* __restrict__ vt,
                                                 unsigned short* __restrict__ ob,
                                                 const int* __restrict__ wptr) {
    __shared__ __align__(16) unsigned short Ks[64 * 128];    // K tile, swizzled, 16 KB
    __shared__ __align__(16) unsigned short Vs[128 * 64];    // V^T tile, swizzled, 16 KB
    __shared__ __align__(16) unsigned short Ps[4 * 16 * 64]; // per-wave P, swizzled, 8 KB
    int tid  = threadIdx.x;
    int wq   = tid >> 6, lane = tid & 63;
    int lm   = lane & 15, lg = lane >> 4;
    int lm7  = lm & 7;
    // XCD-grouped, heavy-first scheduling
    int gid  = blockIdx.x;
    int xcd  = gid & 7, slot = gid >> 3;
    int bh   = xcd * 4 + (slot >> 5);
    int b    = bh >> 4, h = bh & 15;
    int q0   = (31 - (slot & 31)) * AQT;
    int W    = *wptr;
    unsigned short* PsW = &Ps[wq * 1024];

    // Q B-fragments (16 queries/wave); 1/sqrt(d) pre-folded into Q
    bfv8 qa[4];
    {
        const unsigned short* qp = qb + (size_t)(b * SEQ + q0 + wq * 16 + lm) * DMODEL + h * HEADD + lg * 8;
#pragma unroll
        for (int kk = 0; kk < 4; ++kk) qa[kk] = *(const bfv8*)(qp + kk * 32);
    }

    f32x4 o[8];
    f32x4 z = {0.f, 0.f, 0.f, 0.f};
#pragma unroll
    for (int n = 0; n < 8; ++n) o[n] = z;
    float mrow = -1e30f, lrow = 0.f;   // per-lane state for query lm (replicated over lg)

    const unsigned short* kbase = kb + (size_t)(b * SEQ) * DMODEL + h * HEADD;
    const unsigned short* vbase = vt + (size_t)((b * NHEADS + h) * HEADD) * SEQ;

    int kt_lo = max(0, q0 - W) & ~(AKT - 1);
    int qi = q0 + wq * 16 + lm;

    for (int kt = kt_lo; kt < q0 + AQT; kt += AKT) {
        __syncthreads();
        stage_n<4, 4>(kbase + (size_t)kt * DMODEL, Ks, DMODEL, wq, lane);  // 64 x 128
        stage_n<3, 4>(vbase + kt, Vs, SEQ, wq, lane);                      // 128 x 64
        __syncthreads();

        // S^T = K Q^T : D[m=key][n=query], 64x16 per wave
        f32x4 s[4];
#pragma unroll
        for (int j = 0; j < 4; ++j) s[j] = z;
#pragma unroll
        for (int kk = 0; kk < 4; ++kk) {
#pragma unroll
            for (int j = 0; j < 4; ++j) {
                int ck = (kk * 4 + lg) ^ lm7;
                bfv8 af = *(const bfv8*)&Ks[(j * 16 + lm) * 128 + ck * 8];
                s[j] = __builtin_amdgcn_mfma_f32_16x16x32_bf16(af, qa[kk], s[j], 0, 0, 0);
            }
        }
        // mask only edge tiles (wave-uniform branch)
        if ((kt + 63 >= q0) || (kt < q0 + 63 - W)) {
#pragma unroll
            for (int j = 0; j < 4; ++j) {
                int kj0 = kt + j * 16 + lg * 4;
#pragma unroll
                for (int r = 0; r < 4; ++r) {
                    bool ok = (kj0 + r <= qi) && (kj0 + r >= qi - W);
                    s[j][r] = ok ? s[j][r] : -1e30f;
                }
            }
        }
        // online softmax: one query per lane, reduce across lg (masks 16, 32)
        float mx = -1e30f;
#pragma unroll
        for (int j = 0; j < 4; ++j)
#pragma unroll
            for (int r = 0; r < 4; ++r) mx = fmaxf(mx, s[j][r]);
        mx = fmaxf(mx, __shfl_xor(mx, 16));
        mx = fmaxf(mx, __shfl_xor(mx, 32));
        float mnew  = fmaxf(mrow, mx);
        float alpha = __expf(mrow - mnew);
        mrow = mnew;
        float ls = 0.f;
#pragma unroll
        for (int j = 0; j < 4; ++j) {
            float p0 = __expf(s[j][0] - mnew);
            float p1 = __expf(s[j][1] - mnew);
            float p2 = __expf(s[j][2] - mnew);
            float p3 = __expf(s[j][3] - mnew);
            ls += (p0 + p1) + (p2 + p3);
            // P^T C-layout rows = 4 consecutive keys -> one packed b64 store
            int c0 = (j * 2 + (lg >> 1)) ^ lm7;
            uint2 wv;
            wv.x = pk2(p0, p1);
            wv.y = pk2(p2, p3);
            *(uint2*)&PsW[lm * 64 + c0 * 8 + (lg & 1) * 4] = wv;
        }
        ls += __shfl_xor(ls, 16);
        ls += __shfl_xor(ls, 32);
        lrow = lrow * alpha + ls;
        // broadcast alpha from softmax layout (query=lm) to O layout (query=lg*4+r)
        float al[4];
#pragma unroll
        for (int r = 0; r < 4; ++r) al[r] = __shfl(alpha, lg * 4 + r);
#pragma unroll
        for (int n = 0; n < 8; ++n)
#pragma unroll
            for (int r = 0; r < 4; ++r) o[n][r] *= al[r];
        // O += P V : A = P (wave-private LDS, same-wave ordering), B = V^T
#pragma unroll
        for (int k2 = 0; k2 < 2; ++k2) {
            int cc = (k2 * 4 + lg) ^ lm7;
            bfv8 pa = *(const bfv8*)&PsW[lm * 64 + cc * 8];
#pragma unroll
            for (int n = 0; n < 8; ++n) {
                bfv8 vf = *(const bfv8*)&Vs[(n * 16 + lm) * 64 + cc * 8];
                o[n] = __builtin_amdgcn_mfma_f32_16x16x32_bf16(pa, vf, o[n], 0, 0, 0);
            }
        }
    }
    // epilogue
    float linv[4];
#pragma unroll
    for (int r = 0; r < 4; ++r) linv[r] = 1.0f / __shfl(lrow, lg * 4 + r);
    int qrow = q0 + wq * 16 + lg * 4;
    unsigned short* op = ob + (size_t)(b * SEQ + qrow) * DMODEL + h * HEADD + lm;
#pragma unroll
    for (int n = 0; n < 8; ++n)
#pragma unroll
        for (int r = 0; r < 4; ++r)
            op[(size_t)r * DMODEL + n * 16] = f2bf(o[n][r] * linv[r]);
}

// ---------- launch ----------
extern "C" void kernel_launch(void* const* d_in, const int* in_sizes, int n_in,
                              void* d_out, int out_size, void* d_ws, size_t ws_size,
                              hipStream_t stream) {
    const float* x   = (const float*)d_in[0];
    const float* wq  = (const float*)d_in[1];
    const float* wk  = (const float*)d_in[2];
    const float* wv  = (const float*)d_in[3];
    const float* wo  = (const float*)d_in[4];
    const float* qnw = (const float*)d_in[5];
    const float* knw = (const float*)d_in[6];
    const int*   wsz = (const int*)d_in[7];
    float* out = (float*)d_out;

    // workspace layout (~101 MB); cvt_all dst = [xb | w1 | w2 | w3 | w4] contiguous
    char* ws = (char*)d_ws;
    unsigned short* xb  = (unsigned short*)(ws);                 // 16.78 MB (x bf16; reused for attn out)
    unsigned short* w1  = (unsigned short*)(ws + 16777216);      // wq \  contiguous ->
    unsigned short* w4  = (unsigned short*)(ws + 41943040);      // wo
    unsigned short* qbf = (unsigned short*)(ws + 50331648);      // 16.78 MB bf16 Q
    unsigned short* kbf = (unsigned short*)(ws + 67108864);      // 16.78 MB bf16 K
    unsigned short* vtb = (unsigned short*)(ws + 83886080);      // 16.78 MB bf16 V^T

    cvt_all<<<24576, 256, 0, stream>>>(x, wq, wk, wv, wo, xb);

    gemm_qkv<<<dim3(3 * DMODEL / 192, MROWS / 256), 512, 0, stream>>>(xb, w1, qbf, kbf, vtb);

    rope_ln_ip<<<dim3(MROWS * NHEADS / 4, 2), 256, 0, stream>>>(qbf, kbf, qnw, knw);

    attn_mfma<<<(SEQ / AQT) * NHEADS * BATCH, 256, 0, stream>>>(qbf, kbf, vtb, xb, wsz);

    gemm_bt<<<dim3(DMODEL / 128, MROWS / 128), 256, 0, stream>>>(xb, w4, out, MROWS, DMODEL, DMODEL);
}